// Round 13
// baseline (352.588 us; speedup 1.0000x reference)
//
#include <hip/hip_runtime.h>

#define NUM_USERS 100000
#define NUM_ITEMS 50000
#define NUM_OTHERS 20000
#define N_NODES 170000   // NUM_USERS + NUM_ITEMS + NUM_OTHERS
#define DIM 64
#define NNZ 5000000
#define BATCH 8192

#define BSHIFT 9
#define RPB (1 << BSHIFT)                       // 512 rows per bucket
#define NBUCK ((N_NODES + RPB - 1) / RPB)       // 333 buckets
#define COLMASK 0x3FFFF                         // 18 bits for col (N_NODES < 2^18)
#define BCAPSHIFT 14
#define BCAP (1 << BCAPSHIFT)                   // 16384 slots/bucket (mean 15059, +10.8 sigma)
#define NBLK 512                                // scatter chunks
#define SSBS 1024                               // scatter block threads
#define CHUNK ((NNZ + NBLK - 1) / NBLK)         // 9766 edges per block (< 65536 -> ushort idx)
#define SPMM_BLOCKS ((N_NODES + 3) / 4)         // 42500
#define GADD_BLOCKS ((BATCH * 16) / 256)        // 512

typedef float f32x2 __attribute__((ext_vector_type(2)));

// fp32 -> bf16 round-to-nearest-even
static __device__ __forceinline__ unsigned f2bf(float f) {
    unsigned u = __float_as_uint(f);
    u = (u + 0x7fff + ((u >> 16) & 1)) >> 16;
    return u;
}
static __device__ __forceinline__ float bflo(unsigned u) {   // low ushort -> f32
    return __uint_as_float(u << 16);
}
static __device__ __forceinline__ float bfhi(unsigned u) {   // high ushort -> f32
    return __uint_as_float(u & 0xFFFF0000u);
}

// ---------------------------------------------------------------------------
// Fused: cur0 = concat(embs)->bf16  (blocks 0..2047, grid-stride)
//        uacc/iacc = layer-0 batch embeddings (blocks 2048..2559)
// ---------------------------------------------------------------------------
__global__ void build_cur0_init(const float* __restrict__ ue,
                                const float* __restrict__ ie,
                                const float* __restrict__ oe,
                                ushort4* __restrict__ cur,
                                const int* __restrict__ users,
                                const int* __restrict__ items,
                                float4* __restrict__ uacc,
                                float4* __restrict__ iacc) {
    if (blockIdx.x < 2048) {
        const int total = N_NODES * (DIM / 4);
        for (int i = blockIdx.x * 256 + threadIdx.x; i < total; i += 2048 * 256) {
            const int node = i >> 4;
            const int sub  = i & 15;
            const float* src;
            if (node < NUM_USERS)                  src = ue + (size_t)node * DIM;
            else if (node < NUM_USERS + NUM_ITEMS) src = ie + (size_t)(node - NUM_USERS) * DIM;
            else                                   src = oe + (size_t)(node - NUM_USERS - NUM_ITEMS) * DIM;
            const float4 f = reinterpret_cast<const float4*>(src)[sub];
            ushort4 o;
            o.x = (unsigned short)f2bf(f.x); o.y = (unsigned short)f2bf(f.y);
            o.z = (unsigned short)f2bf(f.z); o.w = (unsigned short)f2bf(f.w);
            cur[i] = o;
        }
    } else {
        const int i = (blockIdx.x - 2048) * 256 + threadIdx.x;   // < 131072
        const int b = i >> 4;
        const int sub = i & 15;
        uacc[i] = reinterpret_cast<const float4*>(ue + (size_t)users[b] * DIM)[sub];
        iacc[i] = reinterpret_cast<const float4*>(ie + (size_t)items[b] * DIM)[sub];
    }
}

// ---------------------------------------------------------------------------
// Pass 1: index-staged bucket scatter. Per block: LDS histogram of its
// 9766-edge chunk, 512-wide scan -> local bucket layout, counting-sort the
// chunk-local INDICES (2B each) into LDS bucket-major order, reserve global
// ranges (1 atomic per touched bucket), then write out COALESCED — loop i
// ascending maps to ascending slots in each bucket's region; edge fields are
// re-read from the L1/L2-hot 39KB chunk window. LDS ~26KB -> 2 blocks/CU.
// Entry: .x = (local_row << 18) | col, .y = val bits.
// ---------------------------------------------------------------------------
__global__ __launch_bounds__(SSBS) void bucket_scatter(const int* __restrict__ rows,
                                                       const int* __restrict__ cols,
                                                       const float* __restrict__ vals,
                                                       int* __restrict__ bucket_cnt,
                                                       int2* __restrict__ bkt) {
    __shared__ unsigned short stageIdx[CHUNK];   // 19.5 KB
    __shared__ int h[NBUCK];
    __shared__ int lstart[NBUCK];
    __shared__ int lcur[NBUCK];
    __shared__ int gbias[NBUCK];
    __shared__ int scanbuf[512];
    const int t = threadIdx.x;
    const int s = blockIdx.x * CHUNK;
    const int e = min(s + CHUNK, NNZ);
    const int n = e - s;

    for (int i = t; i < NBUCK; i += SSBS) h[i] = 0;
    __syncthreads();
    for (int i = s + t; i < e; i += SSBS)
        atomicAdd(&h[rows[i] >> BSHIFT], 1);
    __syncthreads();

    // 512-wide exclusive scan over the 333 bucket counts
    int v = 0;
    if (t < 512) { v = (t < NBUCK) ? h[t] : 0; scanbuf[t] = v; }
    __syncthreads();
    int acc = v;
    for (int off = 1; off < 512; off <<= 1) {
        int add = 0;
        if (t < 512 && t >= off) add = scanbuf[t - off];
        __syncthreads();
        if (t < 512) { acc += add; scanbuf[t] = acc; }
        __syncthreads();
    }
    if (t < NBUCK) {
        const int excl = acc - v;
        lstart[t] = excl;
        lcur[t]   = excl;
        const int gb = v ? atomicAdd(&bucket_cnt[t], v) : 0;
        gbias[t] = gb - excl;
    }
    __syncthreads();

    // counting-sort chunk-local indices into LDS (bucket-major)
    for (int i = s + t; i < e; i += SSBS) {
        const int bk = rows[i] >> BSHIFT;
        const int pos = atomicAdd(&lcur[bk], 1);
        stageIdx[pos] = (unsigned short)(i - s);
    }
    __syncthreads();

    // coalesced write-out; rows/cols/vals re-reads hit the hot chunk window
    for (int i = t; i < n; i += SSBS) {
        const int idx = s + (int)stageIdx[i];
        const int r = rows[idx];
        const int bk = r >> BSHIFT;
        bkt[((size_t)bk << BCAPSHIFT) + gbias[bk] + i] =
            make_int2(((r & (RPB - 1)) << 18) | cols[idx], __float_as_int(vals[idx]));
    }
}

// ---------------------------------------------------------------------------
// Pass 2: per-bucket counting sort -> final CSR inside the bucket's fixed
// region. 333 blocks x 1024 threads (~15K edges each). Entry .x = col<<7
// (byte offset). rowinfo[row] = (abs_start << 8) | exact_len (len < 256).
// ---------------------------------------------------------------------------
__global__ __launch_bounds__(1024) void bucket_to_csr(const int* __restrict__ bucket_cnt,
                                                      const int2* __restrict__ bkt,
                                                      unsigned* __restrict__ rowinfo,
                                                      int2* __restrict__ packed) {
    __shared__ int cnt[RPB];
    __shared__ int rs[RPB];
    __shared__ int scan[RPB];
    const int k = blockIdx.x;
    const int rbase = k << BSHIFT;
    const int nvalid = min(RPB, N_NODES - rbase);
    const int n = bucket_cnt[k];
    const int2* __restrict__ src = bkt + ((size_t)k << BCAPSHIFT);
    int2* __restrict__ dst = packed + ((size_t)k << BCAPSHIFT);
    const int t = threadIdx.x;

    if (t < RPB) cnt[t] = 0;
    __syncthreads();
    for (int i = t; i < n; i += 1024)
        atomicAdd(&cnt[src[i].x >> 18], 1);
    __syncthreads();

    // exclusive scan of 512 counts (Hillis-Steele, threads 0..511)
    int v = 0, acc = 0;
    if (t < RPB) { v = cnt[t]; acc = v; scan[t] = v; }
    __syncthreads();
    for (int off = 1; off < RPB; off <<= 1) {
        int add = 0;
        if (t < RPB && t >= off) add = scan[t - off];
        __syncthreads();
        if (t < RPB) { acc += add; scan[t] = acc; }
        __syncthreads();
    }
    if (t < RPB) {
        const int excl = acc - v;
        rs[t] = excl;
        if (t < nvalid)
            rowinfo[rbase + t] = ((unsigned)((k << BCAPSHIFT) + excl) << 8) | (unsigned)v;
    }
    __syncthreads();

    // scatter; atomicAdd on rs yields sequential positions within each row
    for (int i = t; i < n; i += 1024) {
        const int2 pk = src[i];
        const int lr = pk.x >> 18;
        const int pos = atomicAdd(&rs[lr], 1);
        dst[pos] = make_int2((pk.x & COLMASK) << 7, pk.y);
    }
}

// ---------------------------------------------------------------------------
// SpMM gather core (frozen round-6 shape): 32 edge-slots/iter, 8 lanes/edge,
// 16B/lane; masked tail slots clamp to byte-offset 0 (L1-resident x[0] line).
// ---------------------------------------------------------------------------
static __device__ __forceinline__ void spmm_row_accum(
        const unsigned long long* __restrict__ packed,
        const unsigned short* __restrict__ x,
        int s, int e, int g, int d8b,
        f32x2& a0, f32x2& a1, f32x2& a2, f32x2& a3) {
    const char* xb = (const char*)x;
    for (int i = s; i < e; i += 32) {
        const int j0 = i + g;
        const int j1 = j0 + 8;
        const int j2 = j0 + 16;
        const int j3 = j0 + 24;
        const unsigned long long p0 = __builtin_nontemporal_load(packed + j0);
        const unsigned long long p1 = __builtin_nontemporal_load(packed + j1);
        const unsigned long long p2 = __builtin_nontemporal_load(packed + j2);
        const unsigned long long p3 = __builtin_nontemporal_load(packed + j3);
        const unsigned c0 = ((j0 < e) ? (unsigned)(p0 & 0xFFFFFFFFu) : 0u) + d8b;
        const unsigned c1 = ((j1 < e) ? (unsigned)(p1 & 0xFFFFFFFFu) : 0u) + d8b;
        const unsigned c2 = ((j2 < e) ? (unsigned)(p2 & 0xFFFFFFFFu) : 0u) + d8b;
        const unsigned c3 = ((j3 < e) ? (unsigned)(p3 & 0xFFFFFFFFu) : 0u) + d8b;
        const float v0 = (j0 < e) ? __uint_as_float((unsigned)(p0 >> 32)) : 0.f;
        const float v1 = (j1 < e) ? __uint_as_float((unsigned)(p1 >> 32)) : 0.f;
        const float v2 = (j2 < e) ? __uint_as_float((unsigned)(p2 >> 32)) : 0.f;
        const float v3 = (j3 < e) ? __uint_as_float((unsigned)(p3 >> 32)) : 0.f;
        const uint4 x0 = *reinterpret_cast<const uint4*>(xb + c0);
        const uint4 x1 = *reinterpret_cast<const uint4*>(xb + c1);
        const uint4 x2 = *reinterpret_cast<const uint4*>(xb + c2);
        const uint4 x3 = *reinterpret_cast<const uint4*>(xb + c3);
        const f32x2 w0 = {v0, v0}, w1 = {v1, v1}, w2 = {v2, v2}, w3 = {v3, v3};
        a0 += w0 * (f32x2){bflo(x0.x), bfhi(x0.x)};
        a1 += w0 * (f32x2){bflo(x0.y), bfhi(x0.y)};
        a2 += w0 * (f32x2){bflo(x0.z), bfhi(x0.z)};
        a3 += w0 * (f32x2){bflo(x0.w), bfhi(x0.w)};
        a0 += w1 * (f32x2){bflo(x1.x), bfhi(x1.x)};
        a1 += w1 * (f32x2){bflo(x1.y), bfhi(x1.y)};
        a2 += w1 * (f32x2){bflo(x1.z), bfhi(x1.z)};
        a3 += w1 * (f32x2){bflo(x1.w), bfhi(x1.w)};
        a0 += w2 * (f32x2){bflo(x2.x), bfhi(x2.x)};
        a1 += w2 * (f32x2){bflo(x2.y), bfhi(x2.y)};
        a2 += w2 * (f32x2){bflo(x2.z), bfhi(x2.z)};
        a3 += w2 * (f32x2){bflo(x2.w), bfhi(x2.w)};
        a0 += w3 * (f32x2){bflo(x3.x), bfhi(x3.x)};
        a1 += w3 * (f32x2){bflo(x3.y), bfhi(x3.y)};
        a2 += w3 * (f32x2){bflo(x3.z), bfhi(x3.z)};
        a3 += w3 * (f32x2){bflo(x3.w), bfhi(x3.w)};
    }
}

static __device__ __forceinline__ void butterfly8(f32x2& a0, f32x2& a1,
                                                  f32x2& a2, f32x2& a3) {
    #pragma unroll
    for (int off = 8; off < 64; off <<= 1) {
        a0.x += __shfl_xor(a0.x, off); a0.y += __shfl_xor(a0.y, off);
        a1.x += __shfl_xor(a1.x, off); a1.y += __shfl_xor(a1.y, off);
        a2.x += __shfl_xor(a2.x, off); a2.y += __shfl_xor(a2.y, off);
        a3.x += __shfl_xor(a3.x, off); a3.y += __shfl_xor(a3.y, off);
    }
}

// ---------------------------------------------------------------------------
// Full SpMM: one wave per row. Blocks >= SPMM_BLOCKS (layer-2 launch only)
// perform the PREVIOUS layer's batch gather_add from this kernel's INPUT x.
// ---------------------------------------------------------------------------
__global__ __launch_bounds__(256) void spmm_csr8(const unsigned* __restrict__ rowinfo,
                                                 const unsigned long long* __restrict__ packed,
                                                 const unsigned short* __restrict__ x,
                                                 unsigned short* __restrict__ y,
                                                 const int* __restrict__ users,
                                                 const int* __restrict__ items,
                                                 float4* __restrict__ uacc4,
                                                 float4* __restrict__ iacc4) {
    if (blockIdx.x >= SPMM_BLOCKS) {
        const int i = (blockIdx.x - SPMM_BLOCKS) * 256 + threadIdx.x;  // < 131072
        const int b = i >> 4;
        const int sub = i & 15;
        const int un = users[b];
        const int in = NUM_USERS + items[b];
        float4 a = uacc4[i];
        const ushort4 yu = *reinterpret_cast<const ushort4*>(x + (size_t)un * DIM + sub * 4);
        a.x += bflo(yu.x); a.y += bflo(yu.y); a.z += bflo(yu.z); a.w += bflo(yu.w);
        uacc4[i] = a;
        float4 c = iacc4[i];
        const ushort4 yi = *reinterpret_cast<const ushort4*>(x + (size_t)in * DIM + sub * 4);
        c.x += bflo(yi.x); c.y += bflo(yi.y); c.z += bflo(yi.z); c.w += bflo(yi.w);
        iacc4[i] = c;
        return;
    }
    const int row  = blockIdx.x * 4 + (threadIdx.x >> 6);
    const int lane = threadIdx.x & 63;
    if (row >= N_NODES) return;
    const unsigned info = rowinfo[row];
    const int s = (int)(info >> 8);
    const int e = s + (int)(info & 0xFFu);
    const int g   = lane >> 3;
    const int d8b = (lane & 7) * 16;

    f32x2 a0 = {0, 0}, a1 = {0, 0}, a2 = {0, 0}, a3 = {0, 0};
    spmm_row_accum(packed, x, s, e, g, d8b, a0, a1, a2, a3);
    butterfly8(a0, a1, a2, a3);

    if (lane < 8) {
        uint4 o;
        o.x = f2bf(a0.x) | (f2bf(a0.y) << 16);
        o.y = f2bf(a1.x) | (f2bf(a1.y) << 16);
        o.z = f2bf(a2.x) | (f2bf(a2.y) << 16);
        o.w = f2bf(a3.x) | (f2bf(a3.y) << 16);
        *reinterpret_cast<uint4*>(y + (size_t)row * DIM + lane * 8) = o;
    }
}

// ---------------------------------------------------------------------------
// Layer-3: batch rows only; epilogue folds in the layer-2 gather_add.
// ---------------------------------------------------------------------------
__global__ __launch_bounds__(256) void spmm_batch_final8(const unsigned* __restrict__ rowinfo,
                                                         const unsigned long long* __restrict__ packed,
                                                         const unsigned short* __restrict__ x,
                                                         const int* __restrict__ users,
                                                         const int* __restrict__ items,
                                                         float* __restrict__ uacc,
                                                         float* __restrict__ iacc) {
    const int w    = blockIdx.x * 4 + (threadIdx.x >> 6);   // [0, 2*BATCH)
    const int lane = threadIdx.x & 63;
    if (w >= 2 * BATCH) return;
    const int b = w >> 1;
    const int isItem = w & 1;
    const int row = isItem ? (NUM_USERS + items[b]) : users[b];
    const unsigned info = rowinfo[row];
    const int s = (int)(info >> 8);
    const int e = s + (int)(info & 0xFFu);
    const int g   = lane >> 3;
    const int d8b = (lane & 7) * 16;

    f32x2 a0 = {0, 0}, a1 = {0, 0}, a2 = {0, 0}, a3 = {0, 0};
    spmm_row_accum(packed, x, s, e, g, d8b, a0, a1, a2, a3);
    butterfly8(a0, a1, a2, a3);

    if (lane < 8) {
        const ushort4 xa = *reinterpret_cast<const ushort4*>(x + (size_t)row * DIM + lane * 8);
        const ushort4 xc = *reinterpret_cast<const ushort4*>(x + (size_t)row * DIM + lane * 8 + 4);
        float* dst = (isItem ? iacc : uacc) + (size_t)b * DIM + lane * 8;
        float4 q0 = reinterpret_cast<float4*>(dst)[0];
        float4 q1 = reinterpret_cast<float4*>(dst)[1];
        q0.x += a0.x + bflo(xa.x); q0.y += a0.y + bflo(xa.y);
        q0.z += a1.x + bflo(xa.z); q0.w += a1.y + bflo(xa.w);
        q1.x += a2.x + bflo(xc.x); q1.y += a2.y + bflo(xc.y);
        q1.z += a3.x + bflo(xc.z); q1.w += a3.y + bflo(xc.w);
        reinterpret_cast<float4*>(dst)[0] = q0;
        reinterpret_cast<float4*>(dst)[1] = q1;
    }
}

// ---------------------------------------------------------------------------
// gamma[b] = dot(uacc[b], iacc[b]) / 16
// ---------------------------------------------------------------------------
__global__ void dot_out(const float* __restrict__ uacc,
                        const float* __restrict__ iacc,
                        float* __restrict__ gamma) {
    const int b = blockIdx.x * (blockDim.x / 64) + (threadIdx.x / 64);
    const int lane = threadIdx.x & 63;
    if (b >= BATCH) return;
    float p = uacc[b * DIM + lane] * iacc[b * DIM + lane];
    #pragma unroll
    for (int off = 32; off > 0; off >>= 1) p += __shfl_down(p, off);
    if (lane == 0) gamma[b] = p * 0.0625f;
}

// ---------------------------------------------------------------------------
extern "C" void kernel_launch(void* const* d_in, const int* in_sizes, int n_in,
                              void* d_out, int out_size, void* d_ws, size_t ws_size,
                              hipStream_t stream) {
    const float* ue    = (const float*)d_in[0];
    const float* ie    = (const float*)d_in[1];
    const float* oe    = (const float*)d_in[2];
    const float* vals  = (const float*)d_in[3];
    const int*   rows  = (const int*)d_in[4];
    const int*   cols  = (const int*)d_in[5];
    const int*   users = (const int*)d_in[6];
    const int*   items = (const int*)d_in[7];
    float* out = (float*)d_out;

    // ---- workspace layout ----
    // bkt (43.6 MB) is dead after bucket_to_csr; cur (bf16, 21.8 MB) is
    // aliased on top (build_cur0_init runs after pass 2).
    char* p = (char*)d_ws;
    int2* bkt = (int2*)p;                                      // 43.6 MB
    unsigned short* cur = (unsigned short*)p;                  // 21.76 MB (alias)
    p += ((size_t)NBUCK << BCAPSHIFT) * sizeof(int2);
    unsigned short* nxt = (unsigned short*)p;                  // 21.76 MB
    p += (size_t)N_NODES * DIM * sizeof(unsigned short);
    int2* packed = (int2*)p;                                   // 43.6 MB + tail pad
    p += (((size_t)NBUCK << BCAPSHIFT) + 64) * sizeof(int2);
    unsigned* rowinfo = (unsigned*)p;  p += (size_t)(N_NODES + 4) * sizeof(unsigned);
    int* bucket_cnt = (int*)p;  p += (size_t)(NBUCK + 4) * sizeof(int);
    float* uacc = (float*)p;  p += (size_t)BATCH * DIM * sizeof(float);
    float* iacc = (float*)p;  p += (size_t)BATCH * DIM * sizeof(float);

    // ---- CSR build: 2 passes, fixed-capacity buckets ----
    hipMemsetAsync(bucket_cnt, 0, (size_t)NBUCK * sizeof(int), stream);
    bucket_scatter<<<NBLK, SSBS, 0, stream>>>(rows, cols, vals, bucket_cnt, bkt);
    bucket_to_csr<<<NBUCK, 1024, 0, stream>>>(bucket_cnt, bkt, rowinfo, packed);

    // ---- node matrix (aliased over dead bkt) + accumulator init (fused) ----
    build_cur0_init<<<2048 + GADD_BLOCKS, 256, 0, stream>>>(ue, ie, oe, (ushort4*)cur,
                                                            users, items,
                                                            (float4*)uacc, (float4*)iacc);

    // ---- layer 1: full SpMM ----
    spmm_csr8<<<SPMM_BLOCKS, 256, 0, stream>>>(rowinfo,
                                               (const unsigned long long*)packed,
                                               cur, nxt, users, items,
                                               (float4*)uacc, (float4*)iacc);

    // ---- layer 2: full SpMM + fused layer-1 gather_add ----
    spmm_csr8<<<SPMM_BLOCKS + GADD_BLOCKS, 256, 0, stream>>>(rowinfo,
                                                             (const unsigned long long*)packed,
                                                             nxt, cur, users, items,
                                                             (float4*)uacc, (float4*)iacc);

    // ---- layer 3: batch rows only, with folded layer-2 gather_add ----
    spmm_batch_final8<<<(2 * BATCH) / 4, 256, 0, stream>>>(rowinfo,
                                                           (const unsigned long long*)packed,
                                                           cur, users, items, uacc, iacc);

    // ---- output ----
    dot_out<<<BATCH / 4, 256, 0, stream>>>(uacc, iacc, out);
}

// Round 14
// 305.196 us; speedup vs baseline: 1.1553x; 1.1553x over previous
//
#include <hip/hip_runtime.h>

#define NUM_USERS 100000
#define NUM_ITEMS 50000
#define NUM_OTHERS 20000
#define N_NODES 170000   // NUM_USERS + NUM_ITEMS + NUM_OTHERS
#define DIM 64
#define NNZ 5000000
#define BATCH 8192

#define BSHIFT 10
#define RPB (1 << BSHIFT)                       // 1024 rows per bucket
#define NBUCK ((N_NODES + RPB - 1) / RPB)       // 167 buckets
#define COLMASK 0x3FFFF                         // 18 bits for col (N_NODES < 2^18)
#define BCAPSHIFT 15
#define BCAP (1 << BCAPSHIFT)                   // 32768 slots/bucket (mean 29940, +16 sigma)
#define NBLK 512                                // scatter chunks
#define SSBS 1024                               // scatter/build block threads
#define CHUNK ((NNZ + NBLK - 1) / NBLK)         // 9766 edges per block
#define CUR_BLOCKS 640                          // build blocks: cur0 (grid-stride)
#define INIT_BLOCKS 128                         // build blocks: uacc/iacc init (exact)
#define BGRID (CUR_BLOCKS + INIT_BLOCKS)        // 768 appended blocks
#define SPMM_BLOCKS ((N_NODES + 3) / 4)         // 42500
#define GADD_BLOCKS ((BATCH * 16) / 256)        // 512

typedef float f32x2 __attribute__((ext_vector_type(2)));

// fp32 -> bf16 round-to-nearest-even
static __device__ __forceinline__ unsigned f2bf(float f) {
    unsigned u = __float_as_uint(f);
    u = (u + 0x7fff + ((u >> 16) & 1)) >> 16;
    return u;
}
static __device__ __forceinline__ float bflo(unsigned u) {   // low ushort -> f32
    return __uint_as_float(u << 16);
}
static __device__ __forceinline__ float bfhi(unsigned u) {   // high ushort -> f32
    return __uint_as_float(u & 0xFFFF0000u);
}

// ---------------------------------------------------------------------------
// Fused pass 1:
//   blocks [0, NBLK): LDS-staged bucket scatter (round-12 form — full int2
//     staging, coalesced write-out; write amp ~1.05x).
//   blocks [NBLK, NBLK+CUR_BLOCKS): cur0 = concat(embs)->bf16 (grid-stride).
//   blocks [NBLK+CUR_BLOCKS, NBLK+BGRID): uacc/iacc = layer-0 batch embs.
// Disjoint write sets (bkt/bucket_cnt | cur | uacc/iacc) -> race-free.
// ---------------------------------------------------------------------------
__global__ __launch_bounds__(SSBS) void scatter_build(const int* __restrict__ rows,
                                                      const int* __restrict__ cols,
                                                      const float* __restrict__ vals,
                                                      int* __restrict__ bucket_cnt,
                                                      int2* __restrict__ bkt,
                                                      const float* __restrict__ ue,
                                                      const float* __restrict__ ie,
                                                      const float* __restrict__ oe,
                                                      ushort4* __restrict__ cur,
                                                      const int* __restrict__ users,
                                                      const int* __restrict__ items,
                                                      float4* __restrict__ uacc,
                                                      float4* __restrict__ iacc) {
    __shared__ int2 stage[CHUNK];          // 78.1 KB
    __shared__ int h[NBUCK];
    __shared__ int lstart[NBUCK + 1];
    __shared__ int lcur[NBUCK];
    __shared__ int gbias[NBUCK];
    __shared__ int scanbuf[256];
    const int t = threadIdx.x;

    if (blockIdx.x >= NBLK) {
        const int bb = blockIdx.x - NBLK;
        if (bb < CUR_BLOCKS) {
            // cur0 = concat(user_emb, item_emb, other_emb) -> bf16
            const int total = N_NODES * (DIM / 4);
            for (int i = bb * SSBS + t; i < total; i += CUR_BLOCKS * SSBS) {
                const int node = i >> 4;
                const int sub  = i & 15;
                const float* src;
                if (node < NUM_USERS)                  src = ue + (size_t)node * DIM;
                else if (node < NUM_USERS + NUM_ITEMS) src = ie + (size_t)(node - NUM_USERS) * DIM;
                else                                   src = oe + (size_t)(node - NUM_USERS - NUM_ITEMS) * DIM;
                const float4 f = reinterpret_cast<const float4*>(src)[sub];
                ushort4 o;
                o.x = (unsigned short)f2bf(f.x); o.y = (unsigned short)f2bf(f.y);
                o.z = (unsigned short)f2bf(f.z); o.w = (unsigned short)f2bf(f.w);
                cur[i] = o;
            }
        } else {
            const int i = (bb - CUR_BLOCKS) * SSBS + t;   // < 131072 exactly
            const int b = i >> 4;
            const int sub = i & 15;
            uacc[i] = reinterpret_cast<const float4*>(ue + (size_t)users[b] * DIM)[sub];
            iacc[i] = reinterpret_cast<const float4*>(ie + (size_t)items[b] * DIM)[sub];
        }
        return;
    }

    const int s = blockIdx.x * CHUNK;
    const int e = min(s + CHUNK, NNZ);
    const int n = e - s;

    for (int i = t; i < NBUCK; i += SSBS) h[i] = 0;
    __syncthreads();
    for (int i = s + t; i < e; i += SSBS)
        atomicAdd(&h[rows[i] >> BSHIFT], 1);
    __syncthreads();

    // 256-wide exclusive scan over the 167 bucket counts
    int v = 0;
    if (t < 256) { v = (t < NBUCK) ? h[t] : 0; scanbuf[t] = v; }
    __syncthreads();
    int acc = v;
    for (int off = 1; off < 256; off <<= 1) {
        int add = 0;
        if (t < 256 && t >= off) add = scanbuf[t - off];
        __syncthreads();
        if (t < 256) { acc += add; scanbuf[t] = acc; }
        __syncthreads();
    }
    if (t < NBUCK) {
        const int excl = acc - v;
        lstart[t] = excl;
        lcur[t]   = excl;
        const int gb = v ? atomicAdd(&bucket_cnt[t], v) : 0;
        gbias[t] = gb - excl;
    }
    if (t == 0) lstart[NBUCK] = n;
    __syncthreads();

    // counting-sort the chunk into LDS (bucket-major)
    for (int i = s + t; i < e; i += SSBS) {
        const int r  = rows[i];
        const int bk = r >> BSHIFT;
        const int pos = atomicAdd(&lcur[bk], 1);
        stage[pos] = make_int2(((r & (RPB - 1)) << 18) | cols[i],
                               __float_as_int(vals[i]));
    }
    __syncthreads();

    // coalesced write-out (binary search for bucket)
    for (int i = t; i < n; i += SSBS) {
        int lo = 0, hi = NBUCK;
        while (hi - lo > 1) {
            const int mid = (lo + hi) >> 1;
            if (lstart[mid] <= i) lo = mid; else hi = mid;
        }
        bkt[((size_t)lo << BCAPSHIFT) + gbias[lo] + i] = stage[i];
    }
}

// ---------------------------------------------------------------------------
// Pass 2: per-bucket counting sort -> final CSR inside the bucket's fixed
// region. Entry .x = col<<7 (byte offset). rowinfo[row] = (start<<8) | len.
// ---------------------------------------------------------------------------
__global__ __launch_bounds__(1024) void bucket_to_csr(const int* __restrict__ bucket_cnt,
                                                      const int2* __restrict__ bkt,
                                                      unsigned* __restrict__ rowinfo,
                                                      int2* __restrict__ packed) {
    __shared__ int cnt[RPB];
    __shared__ int rs[RPB];
    __shared__ int scan[RPB];
    const int k = blockIdx.x;
    const int rbase = k << BSHIFT;
    const int nvalid = min(RPB, N_NODES - rbase);
    const int n = bucket_cnt[k];
    const int2* __restrict__ src = bkt + ((size_t)k << BCAPSHIFT);
    int2* __restrict__ dst = packed + ((size_t)k << BCAPSHIFT);
    const int t = threadIdx.x;

    cnt[t] = 0;
    __syncthreads();
    for (int i = t; i < n; i += 1024)
        atomicAdd(&cnt[src[i].x >> 18], 1);
    __syncthreads();

    const int v = cnt[t];
    int acc = v;
    scan[t] = v;
    __syncthreads();
    for (int off = 1; off < 1024; off <<= 1) {
        const int add = (t >= off) ? scan[t - off] : 0;
        __syncthreads();
        acc += add;
        scan[t] = acc;
        __syncthreads();
    }
    const int excl = acc - v;
    rs[t] = excl;
    if (t < nvalid)
        rowinfo[rbase + t] = ((unsigned)((k << BCAPSHIFT) + excl) << 8) | (unsigned)v;
    __syncthreads();

    for (int i = t; i < n; i += 1024) {
        const int2 pk = src[i];
        const int lr = pk.x >> 18;
        const int pos = atomicAdd(&rs[lr], 1);
        dst[pos] = make_int2((pk.x & COLMASK) << 7, pk.y);
    }
}

// ---------------------------------------------------------------------------
// SpMM gather core (frozen round-6 shape): 32 edge-slots/iter, 8 lanes/edge,
// 16B/lane; masked tail slots clamp to byte-offset 0 (L1-resident x[0] line).
// ---------------------------------------------------------------------------
static __device__ __forceinline__ void spmm_row_accum(
        const unsigned long long* __restrict__ packed,
        const unsigned short* __restrict__ x,
        int s, int e, int g, int d8b,
        f32x2& a0, f32x2& a1, f32x2& a2, f32x2& a3) {
    const char* xb = (const char*)x;
    for (int i = s; i < e; i += 32) {
        const int j0 = i + g;
        const int j1 = j0 + 8;
        const int j2 = j0 + 16;
        const int j3 = j0 + 24;
        const unsigned long long p0 = __builtin_nontemporal_load(packed + j0);
        const unsigned long long p1 = __builtin_nontemporal_load(packed + j1);
        const unsigned long long p2 = __builtin_nontemporal_load(packed + j2);
        const unsigned long long p3 = __builtin_nontemporal_load(packed + j3);
        const unsigned c0 = ((j0 < e) ? (unsigned)(p0 & 0xFFFFFFFFu) : 0u) + d8b;
        const unsigned c1 = ((j1 < e) ? (unsigned)(p1 & 0xFFFFFFFFu) : 0u) + d8b;
        const unsigned c2 = ((j2 < e) ? (unsigned)(p2 & 0xFFFFFFFFu) : 0u) + d8b;
        const unsigned c3 = ((j3 < e) ? (unsigned)(p3 & 0xFFFFFFFFu) : 0u) + d8b;
        const float v0 = (j0 < e) ? __uint_as_float((unsigned)(p0 >> 32)) : 0.f;
        const float v1 = (j1 < e) ? __uint_as_float((unsigned)(p1 >> 32)) : 0.f;
        const float v2 = (j2 < e) ? __uint_as_float((unsigned)(p2 >> 32)) : 0.f;
        const float v3 = (j3 < e) ? __uint_as_float((unsigned)(p3 >> 32)) : 0.f;
        const uint4 x0 = *reinterpret_cast<const uint4*>(xb + c0);
        const uint4 x1 = *reinterpret_cast<const uint4*>(xb + c1);
        const uint4 x2 = *reinterpret_cast<const uint4*>(xb + c2);
        const uint4 x3 = *reinterpret_cast<const uint4*>(xb + c3);
        const f32x2 w0 = {v0, v0}, w1 = {v1, v1}, w2 = {v2, v2}, w3 = {v3, v3};
        a0 += w0 * (f32x2){bflo(x0.x), bfhi(x0.x)};
        a1 += w0 * (f32x2){bflo(x0.y), bfhi(x0.y)};
        a2 += w0 * (f32x2){bflo(x0.z), bfhi(x0.z)};
        a3 += w0 * (f32x2){bflo(x0.w), bfhi(x0.w)};
        a0 += w1 * (f32x2){bflo(x1.x), bfhi(x1.x)};
        a1 += w1 * (f32x2){bflo(x1.y), bfhi(x1.y)};
        a2 += w1 * (f32x2){bflo(x1.z), bfhi(x1.z)};
        a3 += w1 * (f32x2){bflo(x1.w), bfhi(x1.w)};
        a0 += w2 * (f32x2){bflo(x2.x), bfhi(x2.x)};
        a1 += w2 * (f32x2){bflo(x2.y), bfhi(x2.y)};
        a2 += w2 * (f32x2){bflo(x2.z), bfhi(x2.z)};
        a3 += w2 * (f32x2){bflo(x2.w), bfhi(x2.w)};
        a0 += w3 * (f32x2){bflo(x3.x), bfhi(x3.x)};
        a1 += w3 * (f32x2){bflo(x3.y), bfhi(x3.y)};
        a2 += w3 * (f32x2){bflo(x3.z), bfhi(x3.z)};
        a3 += w3 * (f32x2){bflo(x3.w), bfhi(x3.w)};
    }
}

static __device__ __forceinline__ void butterfly8(f32x2& a0, f32x2& a1,
                                                  f32x2& a2, f32x2& a3) {
    #pragma unroll
    for (int off = 8; off < 64; off <<= 1) {
        a0.x += __shfl_xor(a0.x, off); a0.y += __shfl_xor(a0.y, off);
        a1.x += __shfl_xor(a1.x, off); a1.y += __shfl_xor(a1.y, off);
        a2.x += __shfl_xor(a2.x, off); a2.y += __shfl_xor(a2.y, off);
        a3.x += __shfl_xor(a3.x, off); a3.y += __shfl_xor(a3.y, off);
    }
}

// ---------------------------------------------------------------------------
// Full SpMM: one wave per row. Blocks >= SPMM_BLOCKS (layer-2 launch only)
// perform the PREVIOUS layer's batch gather_add from this kernel's INPUT x.
// ---------------------------------------------------------------------------
__global__ __launch_bounds__(256) void spmm_csr8(const unsigned* __restrict__ rowinfo,
                                                 const unsigned long long* __restrict__ packed,
                                                 const unsigned short* __restrict__ x,
                                                 unsigned short* __restrict__ y,
                                                 const int* __restrict__ users,
                                                 const int* __restrict__ items,
                                                 float4* __restrict__ uacc4,
                                                 float4* __restrict__ iacc4) {
    if (blockIdx.x >= SPMM_BLOCKS) {
        const int i = (blockIdx.x - SPMM_BLOCKS) * 256 + threadIdx.x;  // < 131072
        const int b = i >> 4;
        const int sub = i & 15;
        const int un = users[b];
        const int in = NUM_USERS + items[b];
        float4 a = uacc4[i];
        const ushort4 yu = *reinterpret_cast<const ushort4*>(x + (size_t)un * DIM + sub * 4);
        a.x += bflo(yu.x); a.y += bflo(yu.y); a.z += bflo(yu.z); a.w += bflo(yu.w);
        uacc4[i] = a;
        float4 c = iacc4[i];
        const ushort4 yi = *reinterpret_cast<const ushort4*>(x + (size_t)in * DIM + sub * 4);
        c.x += bflo(yi.x); c.y += bflo(yi.y); c.z += bflo(yi.z); c.w += bflo(yi.w);
        iacc4[i] = c;
        return;
    }
    const int row  = blockIdx.x * 4 + (threadIdx.x >> 6);
    const int lane = threadIdx.x & 63;
    if (row >= N_NODES) return;
    const unsigned info = rowinfo[row];
    const int s = (int)(info >> 8);
    const int e = s + (int)(info & 0xFFu);
    const int g   = lane >> 3;
    const int d8b = (lane & 7) * 16;

    f32x2 a0 = {0, 0}, a1 = {0, 0}, a2 = {0, 0}, a3 = {0, 0};
    spmm_row_accum(packed, x, s, e, g, d8b, a0, a1, a2, a3);
    butterfly8(a0, a1, a2, a3);

    if (lane < 8) {
        uint4 o;
        o.x = f2bf(a0.x) | (f2bf(a0.y) << 16);
        o.y = f2bf(a1.x) | (f2bf(a1.y) << 16);
        o.z = f2bf(a2.x) | (f2bf(a2.y) << 16);
        o.w = f2bf(a3.x) | (f2bf(a3.y) << 16);
        *reinterpret_cast<uint4*>(y + (size_t)row * DIM + lane * 8) = o;
    }
}

// ---------------------------------------------------------------------------
// Layer-3 + output: batch rows only. Epilogue folds the layer-2 gather_add,
// then the block (which owns batch items 2q and 2q+1: waves 0..3 =
// (2q,u),(2q,i),(2q+1,u),(2q+1,i)) exchanges final vectors through LDS and
// computes gamma directly — uacc/iacc are never written back.
// ---------------------------------------------------------------------------
__global__ __launch_bounds__(256) void spmm_batch_dot(const unsigned* __restrict__ rowinfo,
                                                      const unsigned long long* __restrict__ packed,
                                                      const unsigned short* __restrict__ x,
                                                      const int* __restrict__ users,
                                                      const int* __restrict__ items,
                                                      const float* __restrict__ uacc,
                                                      const float* __restrict__ iacc,
                                                      float* __restrict__ gamma) {
    __shared__ float lds[4][64];
    const int wIdx = threadIdx.x >> 6;
    const int w    = blockIdx.x * 4 + wIdx;                 // [0, 2*BATCH)
    const int lane = threadIdx.x & 63;
    const int b = w >> 1;
    const int isItem = w & 1;
    const int row = isItem ? (NUM_USERS + items[b]) : users[b];
    const unsigned info = rowinfo[row];
    const int s = (int)(info >> 8);
    const int e = s + (int)(info & 0xFFu);
    const int g   = lane >> 3;
    const int d8b = (lane & 7) * 16;

    f32x2 a0 = {0, 0}, a1 = {0, 0}, a2 = {0, 0}, a3 = {0, 0};
    spmm_row_accum(packed, x, s, e, g, d8b, a0, a1, a2, a3);
    butterfly8(a0, a1, a2, a3);

    if (lane < 8) {
        // own-row layer-2 value (folded gather_add) + accumulated e0+L1
        const ushort4 xa = *reinterpret_cast<const ushort4*>(x + (size_t)row * DIM + lane * 8);
        const ushort4 xc = *reinterpret_cast<const ushort4*>(x + (size_t)row * DIM + lane * 8 + 4);
        const float* dst = (isItem ? iacc : uacc) + (size_t)b * DIM + lane * 8;
        const float4 q0 = reinterpret_cast<const float4*>(dst)[0];
        const float4 q1 = reinterpret_cast<const float4*>(dst)[1];
        float* o = &lds[wIdx][lane * 8];
        o[0] = q0.x + a0.x + bflo(xa.x);
        o[1] = q0.y + a0.y + bflo(xa.y);
        o[2] = q0.z + a1.x + bflo(xa.z);
        o[3] = q0.w + a1.y + bflo(xa.w);
        o[4] = q1.x + a2.x + bflo(xc.x);
        o[5] = q1.y + a2.y + bflo(xc.y);
        o[6] = q1.z + a3.x + bflo(xc.z);
        o[7] = q1.w + a3.y + bflo(xc.w);
    }
    __syncthreads();

    if (wIdx < 2) {
        float pv = lds[wIdx * 2][lane] * lds[wIdx * 2 + 1][lane];
        #pragma unroll
        for (int off = 32; off > 0; off >>= 1) pv += __shfl_down(pv, off);
        if (lane == 0) gamma[blockIdx.x * 2 + wIdx] = pv * 0.0625f;   // /16
    }
}

// ---------------------------------------------------------------------------
extern "C" void kernel_launch(void* const* d_in, const int* in_sizes, int n_in,
                              void* d_out, int out_size, void* d_ws, size_t ws_size,
                              hipStream_t stream) {
    const float* ue    = (const float*)d_in[0];
    const float* ie    = (const float*)d_in[1];
    const float* oe    = (const float*)d_in[2];
    const float* vals  = (const float*)d_in[3];
    const int*   rows  = (const int*)d_in[4];
    const int*   cols  = (const int*)d_in[5];
    const int*   users = (const int*)d_in[6];
    const int*   items = (const int*)d_in[7];
    float* out = (float*)d_out;

    // ---- workspace layout (no aliasing: cur is written while bkt is live) ----
    char* p = (char*)d_ws;
    int2* bkt = (int2*)p;  p += ((size_t)NBUCK << BCAPSHIFT) * sizeof(int2);   // 43.8 MB
    unsigned short* cur = (unsigned short*)p;                                  // 21.76 MB
    p += (size_t)N_NODES * DIM * sizeof(unsigned short);
    unsigned short* nxt = (unsigned short*)p;                                  // 21.76 MB
    p += (size_t)N_NODES * DIM * sizeof(unsigned short);
    int2* packed = (int2*)p;                                                   // 43.8 MB + pad
    p += (((size_t)NBUCK << BCAPSHIFT) + 64) * sizeof(int2);
    unsigned* rowinfo = (unsigned*)p;  p += (size_t)(N_NODES + 4) * sizeof(unsigned);
    int* bucket_cnt = (int*)p;  p += (size_t)(NBUCK + 4) * sizeof(int);
    float* uacc = (float*)p;  p += (size_t)BATCH * DIM * sizeof(float);
    float* iacc = (float*)p;  p += (size_t)BATCH * DIM * sizeof(float);

    // ---- pass 1 (fused): bucket scatter + cur0 build + accumulator init ----
    hipMemsetAsync(bucket_cnt, 0, (size_t)NBUCK * sizeof(int), stream);
    scatter_build<<<NBLK + BGRID, SSBS, 0, stream>>>(rows, cols, vals, bucket_cnt, bkt,
                                                     ue, ie, oe, (ushort4*)cur,
                                                     users, items,
                                                     (float4*)uacc, (float4*)iacc);

    // ---- pass 2: bucket -> CSR ----
    bucket_to_csr<<<NBUCK, 1024, 0, stream>>>(bucket_cnt, bkt, rowinfo, packed);

    // ---- layer 1: full SpMM ----
    spmm_csr8<<<SPMM_BLOCKS, 256, 0, stream>>>(rowinfo,
                                               (const unsigned long long*)packed,
                                               cur, nxt, users, items,
                                               (float4*)uacc, (float4*)iacc);

    // ---- layer 2: full SpMM + fused layer-1 gather_add ----
    spmm_csr8<<<SPMM_BLOCKS + GADD_BLOCKS, 256, 0, stream>>>(rowinfo,
                                                             (const unsigned long long*)packed,
                                                             nxt, cur, users, items,
                                                             (float4*)uacc, (float4*)iacc);
    // after this: cur holds layer-2 output, uacc/iacc hold e0 + L1

    // ---- layer 3 + dot: batch rows only, gamma written directly ----
    spmm_batch_dot<<<(2 * BATCH) / 4, 256, 0, stream>>>(rowinfo,
                                                        (const unsigned long long*)packed,
                                                        cur, users, items, uacc, iacc, out);
}